// Round 2
// 297.913 us; speedup vs baseline: 1.0072x; 1.0072x over previous
//
#include <hip/hip_runtime.h>

#define POOL 7
#define PP   (POOL * POOL)

// Native clang vector type — required by __builtin_nontemporal_store
// (HIP_vector_type float4 is a class and is rejected).
typedef float floatx4 __attribute__((ext_vector_type(4)));

// ---------------------------------------------------------------------------
// Kernel 1: stable counting sort rank per box within its batch.
// pos[n] = #{m : lvl[m] < lvl[n]} + #{m < n : lvl[m] == lvl[n]}
// One block per batch; N <= 1024 (here N = 1000). ~4 us, not worth tuning.
// ---------------------------------------------------------------------------
__global__ void compute_order_kernel(const int* __restrict__ levels,
                                     int* __restrict__ dst, int N) {
    __shared__ int lvl[1024];
    const int b = blockIdx.x;
    const int n = threadIdx.x;
    const int* L = levels + (size_t)b * N;
    if (n < N) lvl[n] = L[n];
    __syncthreads();
    if (n < N) {
        const int my = lvl[n];
        int pos = 0;
        for (int m = 0; m < N; ++m) {
            const int lm = lvl[m];
            pos += (int)((lm < my) | ((lm == my) & (m < n)));
        }
        dst[(size_t)b * N + n] = pos;
    }
}

// ---------------------------------------------------------------------------
// Kernel 2: crop_and_resize. ONE BLOCK PER BOX, 7 waves (448 threads), wave i
// handles output row gi = i. No __syncthreads anywhere (waves independent).
//
// R4 changes vs R3 (one wave per (box,gi), grid (BN,POOL)):
//  * All 7 gi-waves of a box co-resident on one CU: for levels 2-4 the row
//    step sy < 1 so by(gi) == ty(gi+1) often — adjacent waves re-read the
//    same fm lines; same-CU placement turns those into L1/L2 hits instead of
//    independent LLC/HBM fetches from 7 different XCDs.
//  * Output stores are NON-TEMPORAL: output (100 MB) is write-once and never
//    re-read, but it was evicting the feature maps (178 MB, LLC-resident at
//    256 MiB) from Infinity Cache. nt stores keep fm resident -> corner
//    reads hit LLC, not HBM.
//
// COORDINATE MATH IS DOUBLE PRECISION — the validity test `in_y <= H-1` is
// discontinuous and boxes clipped at 1.0 land within ulps of H-1; matching
// the np reference's f64 mask decisions requires bit-identical f64
// evaluation (same op order). Feature lerp stays f32. (Verified R2: absmax
// 454 -> 0.0156 with this scheme.)
// ---------------------------------------------------------------------------
__global__ __launch_bounds__(448) void roi_align_kernel(
    const float* __restrict__ boxes,
    const float* __restrict__ fm0, const float* __restrict__ fm1,
    const float* __restrict__ fm2, const float* __restrict__ fm3,
    const int* __restrict__ levels, const int* __restrict__ dst,
    float* __restrict__ out, int N, int C) {

    const int box_flat = blockIdx.x;
    const int gi   = threadIdx.x >> 6;  // wave id 0..6 = output row
    const int lane = threadIdx.x & 63;  // lane*4 spans C=256
    const int b = box_flat / N;

    const int lv = levels[box_flat] - 1;  // 1..4 -> 0..3
    const float* fm; int S;
    if      (lv == 0) { fm = fm0; S = 256; }
    else if (lv == 1) { fm = fm1; S = 128; }
    else if (lv == 2) { fm = fm2; S = 64;  }
    else              { fm = fm3; S = 32;  }

    const double y1 = (double)boxes[(size_t)box_flat * 4 + 0];
    const double x1 = (double)boxes[(size_t)box_flat * 4 + 1];
    const double y2 = (double)boxes[(size_t)box_flat * 4 + 2];
    const double x2 = (double)boxes[(size_t)box_flat * 4 + 3];

    const double Hm1 = (double)(S - 1);
    const double sy = (y2 - y1) * Hm1 / (double)(POOL - 1);
    const double sx = (x2 - x1) * Hm1 / (double)(POOL - 1);

    // --- y (fixed for this wave) ---
    const double in_y = y1 * Hm1 + (double)gi * sy;
    const bool vy = (in_y >= 0.0) && (in_y <= Hm1);
    const double fy = floor(in_y);
    const float  wy = (float)(in_y - fy);
    const int ty = (int)fmin(fmax(fy, 0.0), Hm1);
    const int by = min(ty + 1, S - 1);

    const float* fmb  = fm + (size_t)b * S * S * C;
    const float* rowT = fmb + (size_t)ty * S * C;
    const float* rowB = fmb + (size_t)by * S * C;

    const int pos = dst[box_flat];
    float* orow = out + (((size_t)b * N + pos) * PP + (size_t)gi * POOL) * C
                      + lane * 4;

    const double ox = x1 * Hm1;
    const int c = lane * 4;

#pragma unroll
    for (int gj = 0; gj < POOL; ++gj) {
        const double in_x = ox + (double)gj * sx;
        const bool valid = vy && (in_x >= 0.0) && (in_x <= Hm1);

        floatx4 o;
        if (valid) {  // wave-uniform branch: free, skips loads when invalid
            const double fx = floor(in_x);
            const float  wx = (float)(in_x - fx);
            const int lx = (int)fmin(fmax(fx, 0.0), Hm1);
            const int rx = min(lx + 1, S - 1);

            const floatx4 tl = *(const floatx4*)(rowT + (size_t)lx * C + c);
            const floatx4 tr = *(const floatx4*)(rowT + (size_t)rx * C + c);
            const floatx4 bl = *(const floatx4*)(rowB + (size_t)lx * C + c);
            const floatx4 br = *(const floatx4*)(rowB + (size_t)rx * C + c);

            const floatx4 top = tl + (tr - tl) * wx;
            const floatx4 bot = bl + (br - bl) * wx;
            o = top + (bot - top) * wy;
        } else {
            o = (floatx4)0.0f;
        }
        // Non-temporal: output is write-once; don't evict fm from LLC.
        __builtin_nontemporal_store(o, (floatx4*)(orow + (size_t)gj * C));
    }
}

extern "C" void kernel_launch(void* const* d_in, const int* in_sizes, int n_in,
                              void* d_out, int out_size, void* d_ws, size_t ws_size,
                              hipStream_t stream) {
    const float* boxes  = (const float*)d_in[0];
    const float* fm0    = (const float*)d_in[1];
    const float* fm1    = (const float*)d_in[2];
    const float* fm2    = (const float*)d_in[3];
    const float* fm3    = (const float*)d_in[4];
    const int*   levels = (const int*)d_in[5];
    float* out = (float*)d_out;

    const int BN = in_sizes[5];              // B*N = 2000
    const int C  = out_size / (BN * PP);     // 256
    const int B  = in_sizes[1] / (256 * 256 * C);  // fm0 is [B,256,256,C]
    const int N  = BN / B;                   // 1000

    int* dst = (int*)d_ws;                   // BN ints of scratch

    compute_order_kernel<<<B, 1024, 0, stream>>>(levels, dst, N);
    roi_align_kernel<<<BN, 448, 0, stream>>>(
        boxes, fm0, fm1, fm2, fm3, levels, dst, out, N, C);
}